// Round 7
// baseline (733.268 us; speedup 1.0000x reference)
//
#include <hip/hip_runtime.h>
#include <math.h>

// Problem constants (match reference):
#define BB    2
#define NN    8192
#define DD    256
#define NBINS 32
#define BINSZ 256
#define NPROJ 16     // n_bins // 2
#define TOPK  16
#define NPTS  (BB * NN)   // 16384

typedef float vf4 __attribute__((ext_vector_type(4)));

// ---------------------------------------------------------------------------
// K1: bin assignment (numerics unchanged since R1 — absmax 0.0, don't touch).
// ---------------------------------------------------------------------------
__global__ __launch_bounds__(64) void k_bins(const float* __restrict__ x,
                                             const float* __restrict__ cb,
                                             int* __restrict__ bin_idx) {
    __shared__ double cbd[DD][NPROJ];   // 32 KB
    const int t = threadIdx.x;          // 0..63
    for (int q = t; q < DD * 4; q += 64) {
        int d = q >> 2, j4 = q & 3;
        float4 v = *(const float4*)(cb + d * 32 + j4 * 4);
        cbd[d][j4 * 4 + 0] = (double)v.x;
        cbd[d][j4 * 4 + 1] = (double)v.y;
        cbd[d][j4 * 4 + 2] = (double)v.z;
        cbd[d][j4 * 4 + 3] = (double)v.w;
    }
    __syncthreads();

    const int p = blockIdx.x * 64 + t;            // 0..16383 (flat over B,N)
    const float* xr = x + (size_t)p * DD;

    double a[NPROJ];
#pragma unroll
    for (int j = 0; j < NPROJ; ++j) a[j] = 0.0;

    for (int d0 = 0; d0 < DD; d0 += 4) {
        float4 xv = *(const float4*)(xr + d0);
        float xs[4] = {xv.x, xv.y, xv.z, xv.w};
#pragma unroll
        for (int dd = 0; dd < 4; ++dd) {
            double xd = (double)xs[dd];
#pragma unroll
            for (int j = 0; j < NPROJ; ++j)
                a[j] = fma(cbd[d0 + dd][j], xd, a[j]);
        }
    }

    float bv = -INFINITY; int bj = 0;
#pragma unroll
    for (int j = 0; j < NPROJ; ++j) {
        float m = (float)a[j];
        if (m > bv) { bv = m; bj = j; }
    }
#pragma unroll
    for (int j = 0; j < NPROJ; ++j) {
        float m = -(float)a[j];
        if (m > bv) { bv = m; bj = j + NPROJ; }
    }
    bin_idx[p] = bj;
}

// ---------------------------------------------------------------------------
// K2: stable counting sort (unchanged — ~5-8 us).
// ---------------------------------------------------------------------------
__global__ __launch_bounds__(256) void k_sort(const int* __restrict__ bin_idx,
                                              int* __restrict__ order) {
    __shared__ int c[NBINS][256];   // 32 KB
    __shared__ int base[NBINS];
    const int t = threadIdx.x;
    const int b = blockIdx.x;
    const int* bi = bin_idx + b * NN;

    for (int j = 0; j < NBINS; ++j) c[j][t] = 0;
    __syncthreads();

    const int i0 = t * 32;
    for (int i = 0; i < 32; ++i) c[bi[i0 + i]][t]++;
    __syncthreads();

    if (t < NBINS) {
        int s = 0;
        for (int q = 0; q < 256; ++q) s += c[t][q];
        base[t] = s;
    }
    __syncthreads();
    if (t == 0) {
        int run = 0;
        for (int j = 0; j < NBINS; ++j) { int tmp = base[j]; base[j] = run; run += tmp; }
    }
    __syncthreads();
    if (t < NBINS) {
        int run = base[t];
        for (int q = 0; q < 256; ++q) { int tmp = c[t][q]; c[t][q] = run; run += tmp; }
    }
    __syncthreads();

    int* ob = order + b * NN;
    for (int i = 0; i < 32; ++i) {
        int gi = i0 + i;
        int bb = bi[gi];
        int pos = c[bb][t]++;
        ob[pos] = gi;
    }
}

// ---------------------------------------------------------------------------
// K3 v5 — WAVE-SPECIALIZED:
//  Block = 320 threads. Waves 0-3 (t<256): R6's barrier-free fp64 K-loop with
//  ZERO global stores -> their vmcnt waits are pure-load (no store-drain
//  serialization, which was R6's hidden cost: vmcnt is per-wave, in-order).
//  Wave 4 (t>=256): dedicated fill wave — zeroes this block's 32 output rows
//  with plain dwordx4 stores (rocclr-fill-style, 6.1 TB/s proven), no waits.
//  Converging __syncthreads drains each wave's own stores (vmcnt(0)) ->
//  zero stores committed before the value scatter. k_sim ~= max(fill, compute).
//  fp64 FMA order (it->dd4->elem ascending) == reference: absmax 0.0.
// grid = 512 blocks -> 2 blocks/CU; LDS ~71 KB.
// ---------------------------------------------------------------------------
#define RT 32
__global__ __launch_bounds__(320, 2) void k_sim(const float* __restrict__ x,
                                                const int* __restrict__ order,
                                                float* __restrict__ out) {
    __shared__ int   idx[BINSZ];            // 1 KB
    __shared__ float As[RT][260];           // 33.3 KB
    __shared__ float S[RT][BINSZ + 1];      // ~32.9 KB
    __shared__ float tvs[RT][TOPK];         // 2 KB
    __shared__ int   tds[RT][TOPK];         // 2 KB

    const int t   = threadIdx.x;             // 0..319
    const int bid = blockIdx.x;              // 0..511
    const int b   = bid >> 8;
    const int bin = (bid >> 3) & 31;
    const int r0  = (bid & 7) * RT;

    if (t < BINSZ) idx[t] = order[b * NN + bin * BINSZ + t];
    __syncthreads();

    const float* xb = x + (size_t)b * NN * DD;

    // ---- stage A rows r0..r0+31 (all 256 dims) into LDS, coalesced ----
    if (t < 256) {
        const int ar = t >> 3;               // 0..31
        const int ac = t & 7;                // 0..7
        const float* ag = xb + (size_t)idx[r0 + ar] * DD;
#pragma unroll
        for (int q = 0; q < 8; ++q) {
            float4 v = *(const float4*)(ag + (ac + 8 * q) * 4);
            *(float4*)&As[ar][(ac + 8 * q) * 4] = v;
        }
    }
    __syncthreads();   // A-tile ready. Last barrier before the split region.

    if (t < 256) {
        // ================= COMPUTE WAVES (0-3): no global stores =========
        const int rg    = t >> 6;            // wave id -> A reads wave-uniform
        const int cbase = t & 63;
        const float* colp[4];
#pragma unroll
        for (int k = 0; k < 4; ++k)
            colp[k] = xb + (size_t)idx[cbase + 64 * k] * DD;

        double acc[8][4];
#pragma unroll
        for (int r = 0; r < 8; ++r)
#pragma unroll
            for (int k = 0; k < 4; ++k) acc[r][k] = 0.0;

#pragma unroll 1
        for (int it = 0; it < 16; ++it) {
            const int k0 = it * 16;
            float4 bv[4][4];
#pragma unroll
            for (int k = 0; k < 4; ++k)
#pragma unroll
                for (int q = 0; q < 4; ++q)
                    bv[k][q] = *(const float4*)(colp[k] + k0 + q * 4);

#pragma unroll
            for (int dd4 = 0; dd4 < 4; ++dd4) {
                float4 af[8];
#pragma unroll
                for (int rr = 0; rr < 8; ++rr)   // wave-uniform -> broadcast
                    af[rr] = *(const float4*)&As[rg * 8 + rr][k0 + dd4 * 4];
                const float4 b0 = bv[0][dd4], b1 = bv[1][dd4],
                             b2 = bv[2][dd4], b3 = bv[3][dd4];
#pragma unroll
                for (int e = 0; e < 4; ++e) {
                    const double be0 = (double)((e == 0) ? b0.x : (e == 1) ? b0.y : (e == 2) ? b0.z : b0.w);
                    const double be1 = (double)((e == 0) ? b1.x : (e == 1) ? b1.y : (e == 2) ? b1.z : b1.w);
                    const double be2 = (double)((e == 0) ? b2.x : (e == 1) ? b2.y : (e == 2) ? b2.z : b2.w);
                    const double be3 = (double)((e == 0) ? b3.x : (e == 1) ? b3.y : (e == 2) ? b3.z : b3.w);
#pragma unroll
                    for (int rr = 0; rr < 8; ++rr) {
                        const float ae = (e == 0) ? af[rr].x : (e == 1) ? af[rr].y
                                       : (e == 2) ? af[rr].z : af[rr].w;
                        const double ad = (double)ae;
                        acc[rr][0] = fma(ad, be0, acc[rr][0]);
                        acc[rr][1] = fma(ad, be1, acc[rr][1]);
                        acc[rr][2] = fma(ad, be2, acc[rr][2]);
                        acc[rr][3] = fma(ad, be3, acc[rr][3]);
                    }
                }
            }
        }

        // sigmoid (reference fp32 chain) -> S
#pragma unroll
        for (int rr = 0; rr < 8; ++rr)
#pragma unroll
            for (int k = 0; k < 4; ++k) {
                float s32 = (float)acc[rr][k];
                S[rg * 8 + rr][cbase + 64 * k] = 1.0f / (1.0f + expf(-s32));
            }
    } else {
        // ================= FILL WAVE (4): zero the block's 32 rows =======
        const int l = t - 256;               // 0..63
        const vf4 z4 = (vf4)0.0f;
#pragma unroll 1
        for (int r = 0; r < RT; ++r) {
            vf4* orow = (vf4*)(out + ((size_t)b * NN + idx[r0 + r]) * NN);
#pragma unroll
            for (int j = 0; j < 32; ++j)
                orow[j * 64 + l] = z4;       // 64 lanes x 16 B = 1 KB/instr
        }
    }

    __syncthreads();   // per-wave vmcnt(0): fill wave's zeros committed; S ready

    // ---- top-16 per row (desc value, ties -> lowest index) ----
    if (t < RT) {
        float tv[TOPK]; int ti[TOPK];
#pragma unroll
        for (int q = 0; q < TOPK; ++q) { tv[q] = -INFINITY; ti[q] = 0; }
        for (int cc = 0; cc < BINSZ; ++cc) {
            float v = S[t][cc];
            if (v > tv[TOPK - 1]) {
                tv[TOPK - 1] = v; ti[TOPK - 1] = cc;
#pragma unroll
                for (int q = TOPK - 1; q > 0; --q) {
                    if (tv[q] > tv[q - 1]) {
                        float fv = tv[q]; tv[q] = tv[q - 1]; tv[q - 1] = fv;
                        int   fi = ti[q]; ti[q] = ti[q - 1]; ti[q - 1] = fi;
                    }
                }
            }
        }
#pragma unroll
        for (int q = 0; q < TOPK; ++q) {
            tvs[t][q] = tv[q];
            tds[t][q] = idx[ti[q]];
        }
    }
    __syncthreads();   // tvs/tds visible to all

    // ---- scatter 512 values into the zeroed rows ----
    for (int p = t; p < RT * TOPK; p += 320) {
        int r = p >> 4, q = p & 15;
        float* orow = out + ((size_t)b * NN + idx[r0 + r]) * NN;
        orow[tds[r][q]] = tvs[r][q];
    }
}

// ---------------------------------------------------------------------------
extern "C" void kernel_launch(void* const* d_in, const int* in_sizes, int n_in,
                              void* d_out, int out_size, void* d_ws, size_t ws_size,
                              hipStream_t stream) {
    const float* x  = (const float*)d_in[0];
    const float* cb = (const float*)d_in[1];
    float* out      = (float*)d_out;

    int* bin_idx = (int*)d_ws;           // NPTS ints
    int* order   = bin_idx + NPTS;       // NPTS ints

    k_bins<<<NPTS / 64, 64, 0, stream>>>(x, cb, bin_idx);
    k_sort<<<BB, 256, 0, stream>>>(bin_idx, order);
    k_sim<<<BB * NBINS * 8, 320, 0, stream>>>(x, order, out);
}

// Round 8
// 698.799 us; speedup vs baseline: 1.0493x; 1.0493x over previous
//
#include <hip/hip_runtime.h>
#include <math.h>

// Problem constants (match reference):
#define BB    2
#define NN    8192
#define DD    256
#define NBINS 32
#define BINSZ 256
#define NPROJ 16     // n_bins // 2
#define TOPK  16
#define NPTS  (BB * NN)   // 16384

typedef float vf4 __attribute__((ext_vector_type(4)));

// ---------------------------------------------------------------------------
// K1+FILL: 256 blocks x 256 threads (4 waves). Wave 0 bins 64 points
// (numerics identical to R1-R7 — absmax 0.0). ALL waves then zero-fill
// 2 MiB of the output with plain dwordx4 stores. 1024 fill waves chip-wide
// -> ~64 MB aggregate in-flight stores -> HBM-BW-bound fill (R7 lesson:
// few waves => latency-bound fill at ~2 TB/s). End-of-kernel drain makes
// the zeros globally visible before k_sim's scatter (stream ordering).
// ---------------------------------------------------------------------------
__global__ __launch_bounds__(256) void k_bins_fill(const float* __restrict__ x,
                                                   const float* __restrict__ cb,
                                                   int* __restrict__ bin_idx,
                                                   float* __restrict__ out) {
    __shared__ double cbd[DD][NPROJ];   // 32 KB
    const int t   = threadIdx.x;        // 0..255
    const int bid = blockIdx.x;         // 0..255

    for (int q = t; q < DD * 4; q += 256) {
        int d = q >> 2, j4 = q & 3;
        float4 v = *(const float4*)(cb + d * 32 + j4 * 4);
        cbd[d][j4 * 4 + 0] = (double)v.x;
        cbd[d][j4 * 4 + 1] = (double)v.y;
        cbd[d][j4 * 4 + 2] = (double)v.z;
        cbd[d][j4 * 4 + 3] = (double)v.w;
    }
    __syncthreads();

    if (t < 64) {
        // ---- binning (wave 0), numerics unchanged ----
        const int p = bid * 64 + t;                // 0..16383
        const float* xr = x + (size_t)p * DD;

        double a[NPROJ];
#pragma unroll
        for (int j = 0; j < NPROJ; ++j) a[j] = 0.0;

        for (int d0 = 0; d0 < DD; d0 += 4) {
            float4 xv = *(const float4*)(xr + d0);
            float xs[4] = {xv.x, xv.y, xv.z, xv.w};
#pragma unroll
            for (int dd = 0; dd < 4; ++dd) {
                double xd = (double)xs[dd];
#pragma unroll
                for (int j = 0; j < NPROJ; ++j)
                    a[j] = fma(cbd[d0 + dd][j], xd, a[j]);
            }
        }

        float bv = -INFINITY; int bj = 0;
#pragma unroll
        for (int j = 0; j < NPROJ; ++j) {
            float m = (float)a[j];
            if (m > bv) { bv = m; bj = j; }
        }
#pragma unroll
        for (int j = 0; j < NPROJ; ++j) {
            float m = -(float)a[j];
            if (m > bv) { bv = m; bj = j + NPROJ; }
        }
        bin_idx[p] = bj;
    }

    // ---- zero-fill: 2 MiB per block, all 4 waves, plain dwordx4 ----
    {
        const float4 z4 = make_float4(0.f, 0.f, 0.f, 0.f);
        float4* ob = (float4*)out + (size_t)bid * 131072;   // 131072 f4 = 2 MiB
#pragma unroll 4
        for (int j = t; j < 131072; j += 256)
            ob[j] = z4;
    }
}

// ---------------------------------------------------------------------------
// K2: stable counting sort (unchanged — ~6 us).
// ---------------------------------------------------------------------------
__global__ __launch_bounds__(256) void k_sort(const int* __restrict__ bin_idx,
                                              int* __restrict__ order) {
    __shared__ int c[NBINS][256];   // 32 KB
    __shared__ int base[NBINS];
    const int t = threadIdx.x;
    const int b = blockIdx.x;
    const int* bi = bin_idx + b * NN;

    for (int j = 0; j < NBINS; ++j) c[j][t] = 0;
    __syncthreads();

    const int i0 = t * 32;
    for (int i = 0; i < 32; ++i) c[bi[i0 + i]][t]++;
    __syncthreads();

    if (t < NBINS) {
        int s = 0;
        for (int q = 0; q < 256; ++q) s += c[t][q];
        base[t] = s;
    }
    __syncthreads();
    if (t == 0) {
        int run = 0;
        for (int j = 0; j < NBINS; ++j) { int tmp = base[j]; base[j] = run; run += tmp; }
    }
    __syncthreads();
    if (t < NBINS) {
        int run = base[t];
        for (int q = 0; q < 256; ++q) { int tmp = c[t][q]; c[t][q] = run; run += tmp; }
    }
    __syncthreads();

    int* ob = order + b * NN;
    for (int i = 0; i < 32; ++i) {
        int gi = i0 + i;
        int bb = bi[gi];
        int pos = c[bb][t]++;
        ob[pos] = gi;
    }
}

// ---------------------------------------------------------------------------
// K3 v6 = R6's known-good compute structure with the zero-store phase DELETED
// (fill lives in k_bins_fill now). Pure-load K-loop, one pre-loop barrier;
// barriers after it wait only on cheap lgkm/load counts.
// fp64 FMA order (it->dd4->elem ascending) == reference: absmax 0.0.
// grid = 512 blocks x 256 threads -> 2 blocks/CU; LDS ~71 KB.
// ---------------------------------------------------------------------------
#define RT 32
__global__ __launch_bounds__(256, 2) void k_sim(const float* __restrict__ x,
                                                const int* __restrict__ order,
                                                float* __restrict__ out) {
    __shared__ int   idx[BINSZ];            // 1 KB
    __shared__ float As[RT][260];           // 33.3 KB
    __shared__ float S[RT][BINSZ + 1];      // ~32.9 KB
    __shared__ float tvs[RT][TOPK];         // 2 KB
    __shared__ int   tds[RT][TOPK];         // 2 KB

    const int t   = threadIdx.x;             // 0..255
    const int bid = blockIdx.x;              // 0..511
    const int b   = bid >> 8;
    const int bin = (bid >> 3) & 31;
    const int r0  = (bid & 7) * RT;

    idx[t] = order[b * NN + bin * BINSZ + t];
    __syncthreads();

    const float* xb = x + (size_t)b * NN * DD;

    // ---- stage A rows r0..r0+31 (all 256 dims) into LDS, coalesced ----
    {
        const int ar = t >> 3;               // 0..31
        const int ac = t & 7;                // 0..7
        const float* ag = xb + (size_t)idx[r0 + ar] * DD;
#pragma unroll
        for (int q = 0; q < 8; ++q) {
            float4 v = *(const float4*)(ag + (ac + 8 * q) * 4);
            *(float4*)&As[ar][(ac + 8 * q) * 4] = v;
        }
    }

    // compute assignment: rows rg*8..rg*8+7 (block-local), cols (t&63)+64k
    const int rg    = t >> 6;                // wave id -> A reads wave-uniform
    const int cbase = t & 63;
    const float* colp[4];
#pragma unroll
    for (int k = 0; k < 4; ++k)
        colp[k] = xb + (size_t)idx[cbase + 64 * k] * DD;

    double acc[8][4];
#pragma unroll
    for (int r = 0; r < 8; ++r)
#pragma unroll
        for (int k = 0; k < 4; ++k) acc[r][k] = 0.0;

    __syncthreads();   // A-tile ready. Only barrier before the epilogue.

#pragma unroll 1
    for (int it = 0; it < 16; ++it) {
        const int k0 = it * 16;
        float4 bv[4][4];
#pragma unroll
        for (int k = 0; k < 4; ++k)
#pragma unroll
            for (int q = 0; q < 4; ++q)
                bv[k][q] = *(const float4*)(colp[k] + k0 + q * 4);

#pragma unroll
        for (int dd4 = 0; dd4 < 4; ++dd4) {
            float4 af[8];
#pragma unroll
            for (int rr = 0; rr < 8; ++rr)   // wave-uniform -> LDS broadcast
                af[rr] = *(const float4*)&As[rg * 8 + rr][k0 + dd4 * 4];
            const float4 b0 = bv[0][dd4], b1 = bv[1][dd4],
                         b2 = bv[2][dd4], b3 = bv[3][dd4];
#pragma unroll
            for (int e = 0; e < 4; ++e) {
                const double be0 = (double)((e == 0) ? b0.x : (e == 1) ? b0.y : (e == 2) ? b0.z : b0.w);
                const double be1 = (double)((e == 0) ? b1.x : (e == 1) ? b1.y : (e == 2) ? b1.z : b1.w);
                const double be2 = (double)((e == 0) ? b2.x : (e == 1) ? b2.y : (e == 2) ? b2.z : b2.w);
                const double be3 = (double)((e == 0) ? b3.x : (e == 1) ? b3.y : (e == 2) ? b3.z : b3.w);
#pragma unroll
                for (int rr = 0; rr < 8; ++rr) {
                    const float ae = (e == 0) ? af[rr].x : (e == 1) ? af[rr].y
                                   : (e == 2) ? af[rr].z : af[rr].w;
                    const double ad = (double)ae;
                    acc[rr][0] = fma(ad, be0, acc[rr][0]);
                    acc[rr][1] = fma(ad, be1, acc[rr][1]);
                    acc[rr][2] = fma(ad, be2, acc[rr][2]);
                    acc[rr][3] = fma(ad, be3, acc[rr][3]);
                }
            }
        }
    }

    // ---- sigmoid (reference fp32 chain) -> S ----
#pragma unroll
    for (int rr = 0; rr < 8; ++rr)
#pragma unroll
        for (int k = 0; k < 4; ++k) {
            float s32 = (float)acc[rr][k];
            S[rg * 8 + rr][cbase + 64 * k] = 1.0f / (1.0f + expf(-s32));
        }
    __syncthreads();

    // ---- top-16 per row (desc value, ties -> lowest index) ----
    if (t < RT) {
        float tv[TOPK]; int ti[TOPK];
#pragma unroll
        for (int q = 0; q < TOPK; ++q) { tv[q] = -INFINITY; ti[q] = 0; }
        for (int cc = 0; cc < BINSZ; ++cc) {
            float v = S[t][cc];
            if (v > tv[TOPK - 1]) {
                tv[TOPK - 1] = v; ti[TOPK - 1] = cc;
#pragma unroll
                for (int q = TOPK - 1; q > 0; --q) {
                    if (tv[q] > tv[q - 1]) {
                        float fv = tv[q]; tv[q] = tv[q - 1]; tv[q - 1] = fv;
                        int   fi = ti[q]; ti[q] = ti[q - 1]; ti[q - 1] = fi;
                    }
                }
            }
        }
#pragma unroll
        for (int q = 0; q < TOPK; ++q) {
            tvs[t][q] = tv[q];
            tds[t][q] = idx[ti[q]];
        }
    }
    __syncthreads();   // tvs/tds visible

    // ---- scatter 512 values into the (k_bins_fill-)zeroed rows ----
    for (int p = t; p < RT * TOPK; p += 256) {
        int r = p >> 4, q = p & 15;
        float* orow = out + ((size_t)b * NN + idx[r0 + r]) * NN;
        orow[tds[r][q]] = tvs[r][q];
    }
}

// ---------------------------------------------------------------------------
extern "C" void kernel_launch(void* const* d_in, const int* in_sizes, int n_in,
                              void* d_out, int out_size, void* d_ws, size_t ws_size,
                              hipStream_t stream) {
    const float* x  = (const float*)d_in[0];
    const float* cb = (const float*)d_in[1];
    float* out      = (float*)d_out;

    int* bin_idx = (int*)d_ws;           // NPTS ints
    int* order   = bin_idx + NPTS;       // NPTS ints

    k_bins_fill<<<256, 256, 0, stream>>>(x, cb, bin_idx, out);
    k_sort<<<BB, 256, 0, stream>>>(bin_idx, order);
    k_sim<<<BB * NBINS * 8, 256, 0, stream>>>(x, order, out);
}

// Round 9
// 651.960 us; speedup vs baseline: 1.1247x; 1.0718x over previous
//
#include <hip/hip_runtime.h>
#include <math.h>

// Problem constants (match reference):
#define BB    2
#define NN    8192
#define DD    256
#define NBINS 32
#define BINSZ 256
#define NPROJ 16     // n_bins // 2
#define TOPK  16
#define NPTS  (BB * NN)   // 16384

// Fill partition (flat row id = b*NN + point): rows [0,F1) zeroed by k_bins,
// [F1,F2) by k_sort's filler blocks, [F2,NPTS) by k_sim interleaved (R6-style).
#define F1 1280
#define F2 2560

typedef float vf4 __attribute__((ext_vector_type(4)));

// ---------------------------------------------------------------------------
// K1+partial fill: 256 blocks x 256 threads. Wave 0 bins 64 points (numerics
// identical since R1 — absmax 0.0). Then all 4 waves zero rows [bid*5, bid*5+5)
// (batch 0): 160 KB/block — fits entirely in the 4-wave store queue, so the
// fill hides under the binning compute (R7 lesson: small per-block fills are
// fine; big ones at low occupancy are latency-bound).
// ---------------------------------------------------------------------------
__global__ __launch_bounds__(256) void k_bins_fill(const float* __restrict__ x,
                                                   const float* __restrict__ cb,
                                                   int* __restrict__ bin_idx,
                                                   float* __restrict__ out) {
    __shared__ double cbd[DD][NPROJ];   // 32 KB
    const int t   = threadIdx.x;        // 0..255
    const int bid = blockIdx.x;         // 0..255

    for (int q = t; q < DD * 4; q += 256) {
        int d = q >> 2, j4 = q & 3;
        float4 v = *(const float4*)(cb + d * 32 + j4 * 4);
        cbd[d][j4 * 4 + 0] = (double)v.x;
        cbd[d][j4 * 4 + 1] = (double)v.y;
        cbd[d][j4 * 4 + 2] = (double)v.z;
        cbd[d][j4 * 4 + 3] = (double)v.w;
    }
    __syncthreads();

    // ---- fill first (fire-and-forget; drains under the binning compute) ----
    {
        const vf4 z4 = (vf4)0.0f;
#pragma unroll
        for (int q = 0; q < 5; ++q) {
            vf4* orow = (vf4*)(out + (size_t)(bid * 5 + q) * NN);
#pragma unroll
            for (int j = 0; j < 8; ++j)
                orow[j * 256 + t] = z4;     // 8 x 4 KB per row
        }
    }

    if (t < 64) {
        // ---- binning (wave 0), numerics unchanged ----
        const int p = bid * 64 + t;                // 0..16383
        const float* xr = x + (size_t)p * DD;

        double a[NPROJ];
#pragma unroll
        for (int j = 0; j < NPROJ; ++j) a[j] = 0.0;

        for (int d0 = 0; d0 < DD; d0 += 4) {
            float4 xv = *(const float4*)(xr + d0);
            float xs[4] = {xv.x, xv.y, xv.z, xv.w};
#pragma unroll
            for (int dd = 0; dd < 4; ++dd) {
                double xd = (double)xs[dd];
#pragma unroll
                for (int j = 0; j < NPROJ; ++j)
                    a[j] = fma(cbd[d0 + dd][j], xd, a[j]);
            }
        }

        float bv = -INFINITY; int bj = 0;
#pragma unroll
        for (int j = 0; j < NPROJ; ++j) {
            float m = (float)a[j];
            if (m > bv) { bv = m; bj = j; }
        }
#pragma unroll
        for (int j = 0; j < NPROJ; ++j) {
            float m = -(float)a[j];
            if (m > bv) { bv = m; bj = j + NPROJ; }
        }
        bin_idx[p] = bj;
    }
}

// ---------------------------------------------------------------------------
// K2+partial fill: grid 258. Blocks 0-1: stable counting sort (unchanged).
// Blocks 2..257: zero rows [F1 + (bid-2)*5, +5) — 42 MB overlapped with sort.
// ---------------------------------------------------------------------------
__global__ __launch_bounds__(256) void k_sort_fill(const int* __restrict__ bin_idx,
                                                   int* __restrict__ order,
                                                   float* __restrict__ out) {
    const int t   = threadIdx.x;
    const int bid = blockIdx.x;

    if (bid >= 2) {
        const vf4 z4 = (vf4)0.0f;
#pragma unroll
        for (int q = 0; q < 5; ++q) {
            vf4* orow = (vf4*)(out + (size_t)(F1 + (bid - 2) * 5 + q) * NN);
#pragma unroll
            for (int j = 0; j < 8; ++j)
                orow[j * 256 + t] = z4;
        }
        return;
    }

    __shared__ int c[NBINS][256];   // 32 KB
    __shared__ int base[NBINS];
    const int b = bid;
    const int* bi = bin_idx + b * NN;

    for (int j = 0; j < NBINS; ++j) c[j][t] = 0;
    __syncthreads();

    const int i0 = t * 32;
    for (int i = 0; i < 32; ++i) c[bi[i0 + i]][t]++;
    __syncthreads();

    if (t < NBINS) {
        int s = 0;
        for (int q = 0; q < 256; ++q) s += c[t][q];
        base[t] = s;
    }
    __syncthreads();
    if (t == 0) {
        int run = 0;
        for (int j = 0; j < NBINS; ++j) { int tmp = base[j]; base[j] = run; run += tmp; }
    }
    __syncthreads();
    if (t < NBINS) {
        int run = base[t];
        for (int q = 0; q < 256; ++q) { int tmp = c[t][q]; c[t][q] = run; run += tmp; }
    }
    __syncthreads();

    int* ob = order + b * NN;
    for (int i = 0; i < 32; ++i) {
        int gi = i0 + i;
        int bb = bi[gi];
        int pos = c[bb][t]++;
        ob[pos] = gi;
    }
}

// ---------------------------------------------------------------------------
// K3 = R6's best-known structure (662 us config), with one change: the
// interleaved zero-fill SKIPS rows whose flat id (b*NN + point) < F2 — those
// were zeroed by the earlier kernels (stream-ordered before our scatter).
// Work is only removed vs R6. fp64 FMA order unchanged: absmax 0.0.
// grid = 512 x 256 -> 2 blocks/CU; LDS ~71 KB.
// ---------------------------------------------------------------------------
#define RT 32
__global__ __launch_bounds__(256, 2) void k_sim(const float* __restrict__ x,
                                                const int* __restrict__ order,
                                                float* __restrict__ out) {
    __shared__ int   idx[BINSZ];            // 1 KB
    __shared__ float As[RT][260];           // 33.3 KB
    __shared__ float S[RT][BINSZ + 1];      // ~32.9 KB
    __shared__ float tvs[RT][TOPK];         // 2 KB
    __shared__ int   tds[RT][TOPK];         // 2 KB

    const int t   = threadIdx.x;             // 0..255
    const int bid = blockIdx.x;              // 0..511
    const int b   = bid >> 8;
    const int bin = (bid >> 3) & 31;
    const int r0  = (bid & 7) * RT;

    idx[t] = order[b * NN + bin * BINSZ + t];
    __syncthreads();

    const float* xb = x + (size_t)b * NN * DD;

    // ---- stage A rows r0..r0+31 (all 256 dims) into LDS, coalesced ----
    {
        const int ar = t >> 3;               // 0..31
        const int ac = t & 7;                // 0..7
        const float* ag = xb + (size_t)idx[r0 + ar] * DD;
#pragma unroll
        for (int q = 0; q < 8; ++q) {
            float4 v = *(const float4*)(ag + (ac + 8 * q) * 4);
            *(float4*)&As[ar][(ac + 8 * q) * 4] = v;
        }
    }

    // compute assignment: rows rg*8..rg*8+7 (block-local), cols (t&63)+64k
    const int rg    = t >> 6;                // wave id -> A reads wave-uniform
    const int cbase = t & 63;
    const float* colp[4];
#pragma unroll
    for (int k = 0; k < 4; ++k)
        colp[k] = xb + (size_t)idx[cbase + 64 * k] * DD;

    double acc[8][4];
#pragma unroll
    for (int r = 0; r < 8; ++r)
#pragma unroll
        for (int k = 0; k < 4; ++k) acc[r][k] = 0.0;

    const vf4 z4 = (vf4)0.0f;

    __syncthreads();   // A-tile ready. Only barrier before the epilogue.

#pragma unroll 1
    for (int it = 0; it < 16; ++it) {
        const int k0 = it * 16;

        // ---- B-col loads FIRST (older than this iter's stores) ----
        float4 bv[4][4];
#pragma unroll
        for (int k = 0; k < 4; ++k)
#pragma unroll
            for (int q = 0; q < 4; ++q)
                bv[k][q] = *(const float4*)(colp[k] + k0 + q * 4);

        // ---- zero up to 2 rows (skip rows pre-filled by earlier kernels) ----
        {
            const int zr = it * 2;
#pragma unroll
            for (int rr = 0; rr < 2; ++rr) {
                const int pid = idx[r0 + zr + rr];
                if (b * NN + pid >= F2) {    // wave-uniform guard
                    vf4* orow = (vf4*)(out + ((size_t)b * NN + pid) * NN);
#pragma unroll
                    for (int j = 0; j < 8; ++j)
                        __builtin_nontemporal_store(z4, orow + j * 256 + t);
                }
            }
        }

        // ---- FMA: 8 rows x 4 cols, dims strictly ascending ----
#pragma unroll
        for (int dd4 = 0; dd4 < 4; ++dd4) {
            float4 af[8];
#pragma unroll
            for (int rr = 0; rr < 8; ++rr)   // wave-uniform -> LDS broadcast
                af[rr] = *(const float4*)&As[rg * 8 + rr][k0 + dd4 * 4];
            const float4 b0 = bv[0][dd4], b1 = bv[1][dd4],
                         b2 = bv[2][dd4], b3 = bv[3][dd4];
#pragma unroll
            for (int e = 0; e < 4; ++e) {
                const double be0 = (double)((e == 0) ? b0.x : (e == 1) ? b0.y : (e == 2) ? b0.z : b0.w);
                const double be1 = (double)((e == 0) ? b1.x : (e == 1) ? b1.y : (e == 2) ? b1.z : b1.w);
                const double be2 = (double)((e == 0) ? b2.x : (e == 1) ? b2.y : (e == 2) ? b2.z : b2.w);
                const double be3 = (double)((e == 0) ? b3.x : (e == 1) ? b3.y : (e == 2) ? b3.z : b3.w);
#pragma unroll
                for (int rr = 0; rr < 8; ++rr) {
                    const float ae = (e == 0) ? af[rr].x : (e == 1) ? af[rr].y
                                   : (e == 2) ? af[rr].z : af[rr].w;
                    const double ad = (double)ae;
                    acc[rr][0] = fma(ad, be0, acc[rr][0]);
                    acc[rr][1] = fma(ad, be1, acc[rr][1]);
                    acc[rr][2] = fma(ad, be2, acc[rr][2]);
                    acc[rr][3] = fma(ad, be3, acc[rr][3]);
                }
            }
        }
    }

    // ---- sigmoid (reference fp32 chain) -> S ----
#pragma unroll
    for (int rr = 0; rr < 8; ++rr)
#pragma unroll
        for (int k = 0; k < 4; ++k) {
            float s32 = (float)acc[rr][k];
            S[rg * 8 + rr][cbase + 64 * k] = 1.0f / (1.0f + expf(-s32));
        }
    __syncthreads();   // per-wave vmcnt(0) also drains this wave's zero stores

    // ---- top-16 per row (desc value, ties -> lowest index) ----
    if (t < RT) {
        float tv[TOPK]; int ti[TOPK];
#pragma unroll
        for (int q = 0; q < TOPK; ++q) { tv[q] = -INFINITY; ti[q] = 0; }
        for (int cc = 0; cc < BINSZ; ++cc) {
            float v = S[t][cc];
            if (v > tv[TOPK - 1]) {
                tv[TOPK - 1] = v; ti[TOPK - 1] = cc;
#pragma unroll
                for (int q = TOPK - 1; q > 0; --q) {
                    if (tv[q] > tv[q - 1]) {
                        float fv = tv[q]; tv[q] = tv[q - 1]; tv[q - 1] = fv;
                        int   fi = ti[q]; ti[q] = ti[q - 1]; ti[q - 1] = fi;
                    }
                }
            }
        }
#pragma unroll
        for (int q = 0; q < TOPK; ++q) {
            tvs[t][q] = tv[q];
            tds[t][q] = idx[ti[q]];
        }
    }
    __syncthreads();   // tvs/tds visible; all zero stores fully drained

    // ---- scatter 512 values into the zeroed rows ----
    for (int p = t; p < RT * TOPK; p += 256) {
        int r = p >> 4, q = p & 15;
        float* orow = out + ((size_t)b * NN + idx[r0 + r]) * NN;
        orow[tds[r][q]] = tvs[r][q];
    }
}

// ---------------------------------------------------------------------------
extern "C" void kernel_launch(void* const* d_in, const int* in_sizes, int n_in,
                              void* d_out, int out_size, void* d_ws, size_t ws_size,
                              hipStream_t stream) {
    const float* x  = (const float*)d_in[0];
    const float* cb = (const float*)d_in[1];
    float* out      = (float*)d_out;

    int* bin_idx = (int*)d_ws;           // NPTS ints
    int* order   = bin_idx + NPTS;       // NPTS ints

    k_bins_fill<<<256, 256, 0, stream>>>(x, cb, bin_idx, out);
    k_sort_fill<<<258, 256, 0, stream>>>(bin_idx, order, out);
    k_sim<<<BB * NBINS * 8, 256, 0, stream>>>(x, order, out);
}

// Round 10
// 650.191 us; speedup vs baseline: 1.1278x; 1.0027x over previous
//
#include <hip/hip_runtime.h>
#include <math.h>

// Problem constants (match reference):
#define BB    2
#define NN    8192
#define DD    256
#define NBINS 32
#define BINSZ 256
#define NPROJ 16     // n_bins // 2
#define TOPK  16
#define NPTS  (BB * NN)   // 16384

// Fill partition (flat row id = b*NN + point): rows [0,F1) zeroed by k_bins,
// [F1,F2) by k_sort's filler blocks, [F2,NPTS) by k_sim interleaved.
// Balanced so k_sim's fill (~302 MB ~= 50us) matches its compute span, and
// bins/sort become ~19us fill-bound each: graph ~= 88us fill floor + eps.
#define FPB 14                 // fill rows per block (256 blocks per kernel)
#define F1  (256 * FPB)        // 3584
#define F2  (2 * 256 * FPB)    // 7168

typedef float vf4 __attribute__((ext_vector_type(4)));

// ---------------------------------------------------------------------------
// K1+fill: wave 0 bins 64 points (numerics identical since R1 — absmax 0.0);
// all 4 waves zero rows [bid*FPB, (bid+1)*FPB) of batch 0.
// ---------------------------------------------------------------------------
__global__ __launch_bounds__(256) void k_bins_fill(const float* __restrict__ x,
                                                   const float* __restrict__ cb,
                                                   int* __restrict__ bin_idx,
                                                   float* __restrict__ out) {
    __shared__ double cbd[DD][NPROJ];   // 32 KB
    const int t   = threadIdx.x;        // 0..255
    const int bid = blockIdx.x;         // 0..255

    for (int q = t; q < DD * 4; q += 256) {
        int d = q >> 2, j4 = q & 3;
        float4 v = *(const float4*)(cb + d * 32 + j4 * 4);
        cbd[d][j4 * 4 + 0] = (double)v.x;
        cbd[d][j4 * 4 + 1] = (double)v.y;
        cbd[d][j4 * 4 + 2] = (double)v.z;
        cbd[d][j4 * 4 + 3] = (double)v.w;
    }
    __syncthreads();

    // ---- fill first (fire-and-forget; binning compute hides under it) ----
    {
        const vf4 z4 = (vf4)0.0f;
#pragma unroll 1
        for (int q = 0; q < FPB; ++q) {
            vf4* orow = (vf4*)(out + (size_t)(bid * FPB + q) * NN);
#pragma unroll
            for (int j = 0; j < 8; ++j)
                orow[j * 256 + t] = z4;     // 8 x 4 KB per row
        }
    }

    if (t < 64) {
        // ---- binning (wave 0), numerics unchanged ----
        const int p = bid * 64 + t;                // 0..16383
        const float* xr = x + (size_t)p * DD;

        double a[NPROJ];
#pragma unroll
        for (int j = 0; j < NPROJ; ++j) a[j] = 0.0;

        for (int d0 = 0; d0 < DD; d0 += 4) {
            float4 xv = *(const float4*)(xr + d0);
            float xs[4] = {xv.x, xv.y, xv.z, xv.w};
#pragma unroll
            for (int dd = 0; dd < 4; ++dd) {
                double xd = (double)xs[dd];
#pragma unroll
                for (int j = 0; j < NPROJ; ++j)
                    a[j] = fma(cbd[d0 + dd][j], xd, a[j]);
            }
        }

        float bv = -INFINITY; int bj = 0;
#pragma unroll
        for (int j = 0; j < NPROJ; ++j) {
            float m = (float)a[j];
            if (m > bv) { bv = m; bj = j; }
        }
#pragma unroll
        for (int j = 0; j < NPROJ; ++j) {
            float m = -(float)a[j];
            if (m > bv) { bv = m; bj = j + NPROJ; }
        }
        bin_idx[p] = bj;
    }
}

// ---------------------------------------------------------------------------
// K2+fill: grid 258. Blocks 0-1: stable counting sort (unchanged since R1).
// Blocks 2..257: zero rows [F1 + (bid-2)*FPB, +FPB).
// ---------------------------------------------------------------------------
__global__ __launch_bounds__(256) void k_sort_fill(const int* __restrict__ bin_idx,
                                                   int* __restrict__ order,
                                                   float* __restrict__ out) {
    const int t   = threadIdx.x;
    const int bid = blockIdx.x;

    if (bid >= 2) {
        const vf4 z4 = (vf4)0.0f;
#pragma unroll 1
        for (int q = 0; q < FPB; ++q) {
            vf4* orow = (vf4*)(out + (size_t)(F1 + (bid - 2) * FPB + q) * NN);
#pragma unroll
            for (int j = 0; j < 8; ++j)
                orow[j * 256 + t] = z4;
        }
        return;
    }

    __shared__ int c[NBINS][256];   // 32 KB
    __shared__ int base[NBINS];
    const int b = bid;
    const int* bi = bin_idx + b * NN;

    for (int j = 0; j < NBINS; ++j) c[j][t] = 0;
    __syncthreads();

    const int i0 = t * 32;
    for (int i = 0; i < 32; ++i) c[bi[i0 + i]][t]++;
    __syncthreads();

    if (t < NBINS) {
        int s = 0;
        for (int q = 0; q < 256; ++q) s += c[t][q];
        base[t] = s;
    }
    __syncthreads();
    if (t == 0) {
        int run = 0;
        for (int j = 0; j < NBINS; ++j) { int tmp = base[j]; base[j] = run; run += tmp; }
    }
    __syncthreads();
    if (t < NBINS) {
        int run = base[t];
        for (int q = 0; q < 256; ++q) { int tmp = c[t][q]; c[t][q] = run; run += tmp; }
    }
    __syncthreads();

    int* ob = order + b * NN;
    for (int i = 0; i < 32; ++i) {
        int gi = i0 + i;
        int bb = bi[gi];
        int pos = c[bb][t]++;
        ob[pos] = gi;
    }
}

// ---------------------------------------------------------------------------
// K3 = R9 structure (known good), fill guard now flat id >= F2.
// fp64 FMA order unchanged: absmax 0.0. grid 512 x 256 -> 2 blocks/CU.
// ---------------------------------------------------------------------------
#define RT 32
__global__ __launch_bounds__(256, 2) void k_sim(const float* __restrict__ x,
                                                const int* __restrict__ order,
                                                float* __restrict__ out) {
    __shared__ int   idx[BINSZ];            // 1 KB
    __shared__ float As[RT][260];           // 33.3 KB
    __shared__ float S[RT][BINSZ + 1];      // ~32.9 KB
    __shared__ float tvs[RT][TOPK];         // 2 KB
    __shared__ int   tds[RT][TOPK];         // 2 KB

    const int t   = threadIdx.x;             // 0..255
    const int bid = blockIdx.x;              // 0..511
    const int b   = bid >> 8;
    const int bin = (bid >> 3) & 31;
    const int r0  = (bid & 7) * RT;

    idx[t] = order[b * NN + bin * BINSZ + t];
    __syncthreads();

    const float* xb = x + (size_t)b * NN * DD;

    // ---- stage A rows r0..r0+31 (all 256 dims) into LDS, coalesced ----
    {
        const int ar = t >> 3;               // 0..31
        const int ac = t & 7;                // 0..7
        const float* ag = xb + (size_t)idx[r0 + ar] * DD;
#pragma unroll
        for (int q = 0; q < 8; ++q) {
            float4 v = *(const float4*)(ag + (ac + 8 * q) * 4);
            *(float4*)&As[ar][(ac + 8 * q) * 4] = v;
        }
    }

    // compute assignment: rows rg*8..rg*8+7 (block-local), cols (t&63)+64k
    const int rg    = t >> 6;                // wave id -> A reads wave-uniform
    const int cbase = t & 63;
    const float* colp[4];
#pragma unroll
    for (int k = 0; k < 4; ++k)
        colp[k] = xb + (size_t)idx[cbase + 64 * k] * DD;

    double acc[8][4];
#pragma unroll
    for (int r = 0; r < 8; ++r)
#pragma unroll
        for (int k = 0; k < 4; ++k) acc[r][k] = 0.0;

    const vf4 z4 = (vf4)0.0f;

    __syncthreads();   // A-tile ready. Only barrier before the epilogue.

#pragma unroll 1
    for (int it = 0; it < 16; ++it) {
        const int k0 = it * 16;

        // ---- B-col loads FIRST (older than this iter's stores) ----
        float4 bv[4][4];
#pragma unroll
        for (int k = 0; k < 4; ++k)
#pragma unroll
            for (int q = 0; q < 4; ++q)
                bv[k][q] = *(const float4*)(colp[k] + k0 + q * 4);

        // ---- zero up to 2 rows (skip rows pre-filled by earlier kernels) ----
        {
            const int zr = it * 2;
#pragma unroll
            for (int rr = 0; rr < 2; ++rr) {
                const int pid = idx[r0 + zr + rr];
                if (b * NN + pid >= F2) {    // wave-uniform guard
                    vf4* orow = (vf4*)(out + ((size_t)b * NN + pid) * NN);
#pragma unroll
                    for (int j = 0; j < 8; ++j)
                        __builtin_nontemporal_store(z4, orow + j * 256 + t);
                }
            }
        }

        // ---- FMA: 8 rows x 4 cols, dims strictly ascending ----
#pragma unroll
        for (int dd4 = 0; dd4 < 4; ++dd4) {
            float4 af[8];
#pragma unroll
            for (int rr = 0; rr < 8; ++rr)   // wave-uniform -> LDS broadcast
                af[rr] = *(const float4*)&As[rg * 8 + rr][k0 + dd4 * 4];
            const float4 b0 = bv[0][dd4], b1 = bv[1][dd4],
                         b2 = bv[2][dd4], b3 = bv[3][dd4];
#pragma unroll
            for (int e = 0; e < 4; ++e) {
                const double be0 = (double)((e == 0) ? b0.x : (e == 1) ? b0.y : (e == 2) ? b0.z : b0.w);
                const double be1 = (double)((e == 0) ? b1.x : (e == 1) ? b1.y : (e == 2) ? b1.z : b1.w);
                const double be2 = (double)((e == 0) ? b2.x : (e == 1) ? b2.y : (e == 2) ? b2.z : b2.w);
                const double be3 = (double)((e == 0) ? b3.x : (e == 1) ? b3.y : (e == 2) ? b3.z : b3.w);
#pragma unroll
                for (int rr = 0; rr < 8; ++rr) {
                    const float ae = (e == 0) ? af[rr].x : (e == 1) ? af[rr].y
                                   : (e == 2) ? af[rr].z : af[rr].w;
                    const double ad = (double)ae;
                    acc[rr][0] = fma(ad, be0, acc[rr][0]);
                    acc[rr][1] = fma(ad, be1, acc[rr][1]);
                    acc[rr][2] = fma(ad, be2, acc[rr][2]);
                    acc[rr][3] = fma(ad, be3, acc[rr][3]);
                }
            }
        }
    }

    // ---- sigmoid (reference fp32 chain) -> S ----
#pragma unroll
    for (int rr = 0; rr < 8; ++rr)
#pragma unroll
        for (int k = 0; k < 4; ++k) {
            float s32 = (float)acc[rr][k];
            S[rg * 8 + rr][cbase + 64 * k] = 1.0f / (1.0f + expf(-s32));
        }
    __syncthreads();   // per-wave vmcnt(0) also drains this wave's zero stores

    // ---- top-16 per row (desc value, ties -> lowest index) ----
    if (t < RT) {
        float tv[TOPK]; int ti[TOPK];
#pragma unroll
        for (int q = 0; q < TOPK; ++q) { tv[q] = -INFINITY; ti[q] = 0; }
        for (int cc = 0; cc < BINSZ; ++cc) {
            float v = S[t][cc];
            if (v > tv[TOPK - 1]) {
                tv[TOPK - 1] = v; ti[TOPK - 1] = cc;
#pragma unroll
                for (int q = TOPK - 1; q > 0; --q) {
                    if (tv[q] > tv[q - 1]) {
                        float fv = tv[q]; tv[q] = tv[q - 1]; tv[q - 1] = fv;
                        int   fi = ti[q]; ti[q] = ti[q - 1]; ti[q - 1] = fi;
                    }
                }
            }
        }
#pragma unroll
        for (int q = 0; q < TOPK; ++q) {
            tvs[t][q] = tv[q];
            tds[t][q] = idx[ti[q]];
        }
    }
    __syncthreads();   // tvs/tds visible; all zero stores fully drained

    // ---- scatter 512 values into the zeroed rows ----
    for (int p = t; p < RT * TOPK; p += 256) {
        int r = p >> 4, q = p & 15;
        float* orow = out + ((size_t)b * NN + idx[r0 + r]) * NN;
        orow[tds[r][q]] = tvs[r][q];
    }
}

// ---------------------------------------------------------------------------
extern "C" void kernel_launch(void* const* d_in, const int* in_sizes, int n_in,
                              void* d_out, int out_size, void* d_ws, size_t ws_size,
                              hipStream_t stream) {
    const float* x  = (const float*)d_in[0];
    const float* cb = (const float*)d_in[1];
    float* out      = (float*)d_out;

    int* bin_idx = (int*)d_ws;           // NPTS ints
    int* order   = bin_idx + NPTS;       // NPTS ints

    k_bins_fill<<<256, 256, 0, stream>>>(x, cb, bin_idx, out);
    k_sort_fill<<<258, 256, 0, stream>>>(bin_idx, order, out);
    k_sim<<<BB * NBINS * 8, 256, 0, stream>>>(x, order, out);
}